// Round 15
// baseline (1297.055 us; speedup 1.0000x reference)
//
#include <hip/hip_runtime.h>

// ---------- helpers ----------
typedef __attribute__((ext_vector_type(8))) __bf16 bf16x8;
typedef __attribute__((ext_vector_type(8))) unsigned short u16x8;
typedef __attribute__((ext_vector_type(4))) float f32x4;

__device__ inline unsigned short f2bf(float f) {
    union { float f; unsigned int i; } v; v.f = f;
    unsigned int i = v.i;
    unsigned int r = i + 0x7FFFu + ((i >> 16) & 1u);   // RNE
    return (unsigned short)(r >> 16);
}
__device__ inline float bf2f(unsigned short u) {
    union { unsigned int i; float f; } v; v.i = ((unsigned int)u) << 16; return v.f;
}

__device__ inline void gload_lds16(const void* g, void* l) {
    __builtin_amdgcn_global_load_lds(
        (const __attribute__((address_space(1))) unsigned int*)g,
        (__attribute__((address_space(3))) unsigned int*)l, 16, 0, 0);
}

// inline-asm LDS read (32-bit byte offset, dynamic-LDS base 0); invisible to
// the memory legalizer -> no compiler vmcnt/lgkm drains against our pipeline.
__device__ inline bf16x8 ldsrd(unsigned off) {
    bf16x8 r;
    asm volatile("ds_read_b128 %0, %1" : "=v"(r) : "v"(off));
    return r;
}

// ---------- kernel 1: cast x (fp32 -> bf16), exact grid, 8 elems/thread ----------
__global__ __launch_bounds__(256) void cast_x(const float* __restrict__ x,
                                              unsigned short* __restrict__ xb) {
    size_t i = ((size_t)blockIdx.x * 256 + threadIdx.x) * 8;
    float4 v0 = *(const float4*)&x[i];
    float4 v1 = *(const float4*)&x[i + 4];
    ushort4 o0, o1;
    o0.x = f2bf(v0.x); o0.y = f2bf(v0.y); o0.z = f2bf(v0.z); o0.w = f2bf(v0.w);
    o1.x = f2bf(v1.x); o1.y = f2bf(v1.y); o1.z = f2bf(v1.z); o1.w = f2bf(v1.w);
    *(ushort4*)&xb[i] = o0;
    *(ushort4*)&xb[i + 4] = o1;
}

// ---------- kernel 2: fused prep — cast W | acat | bcatT ----------
__global__ __launch_bounds__(256) void prep_all(const float* __restrict__ W,
                                                const float* __restrict__ A,
                                                const float* __restrict__ Bm,
                                                const float* __restrict__ scores,
                                                unsigned short* __restrict__ wcat,
                                                unsigned short* __restrict__ acat,
                                                unsigned short* __restrict__ bcatT) {
    const int blk = blockIdx.x;
    const int tx = threadIdx.x;
    if (blk < 1024) {
        int i = blk * 256 + tx;
        float4 v = ((const float4*)W)[i];
        ushort4 o;
        o.x = f2bf(v.x); o.y = f2bf(v.y); o.z = f2bf(v.z); o.w = f2bf(v.w);
        ((ushort4*)wcat)[i] = o;
    } else if (blk < 1088) {
        int tid = (blk - 1024) * 256 + tx;      // 16384
        int e = tid >> 10;
        int d = tid & 1023;
        float pe = scores[e];
        const float4* src = (const float4*)(A + (size_t)e * 16384 + (size_t)d * 16);
        unsigned short* dst = acat + (size_t)d * 256 + e * 16;
        #pragma unroll
        for (int q = 0; q < 4; ++q) {
            float4 v = src[q];
            ushort4 o;
            o.x = f2bf(pe * v.x); o.y = f2bf(pe * v.y);
            o.z = f2bf(pe * v.z); o.w = f2bf(pe * v.w);
            *(ushort4*)(dst + q * 4) = o;
        }
    } else {
        __shared__ float t[64][65];
        const int bb = blk - 1088;              // 0..63
        const int Dt = (bb & 15) * 64;          // D tile
        const int et = (bb >> 4) * 64;          // er tile
        {
            const int i = tx >> 2;              // er row 0..63
            const int c4 = (tx & 3) * 16;       // D col base
            const float* src = Bm + (size_t)(et + i) * 1024 + Dt + c4;
            #pragma unroll
            for (int q = 0; q < 4; ++q) {
                float4 v = *(const float4*)(src + q * 4);
                t[i][c4 + q * 4 + 0] = v.x; t[i][c4 + q * 4 + 1] = v.y;
                t[i][c4 + q * 4 + 2] = v.z; t[i][c4 + q * 4 + 3] = v.w;
            }
        }
        __syncthreads();
        {
            const int j = tx >> 2;              // D row 0..63
            const int seg = (tx & 3) * 16;      // er col base
            unsigned short* dst = bcatT + (size_t)(Dt + j) * 256 + et + seg;
            #pragma unroll
            for (int q = 0; q < 16; ++q)
                dst[q] = f2bf(t[seg + q][j]);
        }
    }
}

// ---------- kernel 3: mini GEMM  wcat[1024+D][d] = sum_k bcatT[D][k]*acat[d][k] ----------
__global__ __launch_bounds__(256) void mini_gemm(const unsigned short* __restrict__ bcatT,
                                                 const unsigned short* __restrict__ acat,
                                                 unsigned short* __restrict__ wcat) {
    extern __shared__ char lds[];
    const int tid = threadIdx.x;
    const int l = tid & 63;
    const int w = tid >> 6;
    const int wr = w >> 1;        // 0..1 (D half)
    const int wc = w & 1;         // 0..1 (d half)

    const int trow = (blockIdx.x >> 3) * 128;   // D tile
    const int tcol = (blockIdx.x & 7) * 128;    // d tile

    const unsigned rA128 = (unsigned)((wr * 64 + (l & 15)) * 128);
    const unsigned rB128 = 16384u + (unsigned)((wc * 64 + (l & 15)) * 128);
    const unsigned pck0 = (((l >> 4)) ^ (l & 7)) * 16u;
    const unsigned pck1 = ((4 + (l >> 4)) ^ (l & 7)) * 16u;

    const unsigned strow = (unsigned)(tid >> 3);               // 0..31
    const unsigned stchunk = (unsigned)((tid & 7) ^ (strow & 7));
    const unsigned stlds = (unsigned)(tid * 16);

    f32x4 acc[4][4] = {};

    for (int t = 0; t < 4; ++t) {
        #pragma unroll
        for (int h = 0; h < 4; ++h) {
            const unsigned short* ga = bcatT + (size_t)(trow + h * 32 + strow) * 256 + t * 64 + stchunk * 8;
            const unsigned short* gb = acat  + (size_t)(tcol + h * 32 + strow) * 256 + t * 64 + stchunk * 8;
            gload_lds16(ga, lds + h * 4096 + stlds);
            gload_lds16(gb, lds + 16384 + h * 4096 + stlds);
        }
        asm volatile("s_waitcnt vmcnt(0)" ::: "memory");
        __builtin_amdgcn_s_barrier();

        bf16x8 a[4], b[4];
        #pragma unroll
        for (int ks = 0; ks < 2; ++ks) {
            const unsigned pck = ks ? pck1 : pck0;
            #pragma unroll
            for (int mf = 0; mf < 4; ++mf) a[mf] = ldsrd(rA128 + mf * 2048 + pck);
            #pragma unroll
            for (int nf = 0; nf < 4; ++nf) b[nf] = ldsrd(rB128 + nf * 2048 + pck);
            asm volatile("s_waitcnt lgkmcnt(0)" ::: "memory");
            __builtin_amdgcn_sched_barrier(0);
            #pragma unroll
            for (int mf = 0; mf < 4; ++mf)
                #pragma unroll
                for (int nf = 0; nf < 4; ++nf)
                    acc[mf][nf] = __builtin_amdgcn_mfma_f32_16x16x32_bf16(a[mf], b[nf], acc[mf][nf], 0, 0, 0);
        }
        __builtin_amdgcn_s_barrier();
    }

    const int crow0 = trow + wr * 64 + (l >> 4) * 4;   // D
    const int ccol0 = tcol + wc * 64 + (l & 15);       // d
    #pragma unroll
    for (int mf = 0; mf < 4; ++mf) {
        int D = crow0 + mf * 16;
        #pragma unroll
        for (int nf = 0; nf < 4; ++nf) {
            int d = ccol0 + nf * 16;
            f32x4 v = acc[mf][nf];
            #pragma unroll
            for (int j = 0; j < 4; ++j)
                wcat[(size_t)(1024 + D + j) * 1024 + d] = f2bf(v[j]);
        }
    }
}

// ---------- kernel 4: 256x256-tile GEMM, BK=32, 2 blocks/CU, FIXED swizzle ----------
// R13 retry with the conflict bug fixed: XOR key is (row>>1)&3 (not row&3).
// Bank audit (64B rows, 4 chunks): bank_start(r,hk) = (16r + 4(hk^((r>>1)&3)))
// mod 32 -> each of the 8 bank-starts gets exactly 8 of 64 lanes = the wave64
// b128 floor (conflict-free). 64KB LDS dbuf -> 2 blocks/CU (VGPR 96 <= 128):
// two independent barrier domains interleave LDS-read and MFMA phases.
__global__ __launch_bounds__(512, 4) void gemm_2b(const unsigned short* __restrict__ xb,
                                                  const unsigned short* __restrict__ wcat,
                                                  const float* __restrict__ bias,
                                                  float* __restrict__ zout) {
    extern __shared__ char lds[];
    const int tid = threadIdx.x;
    const int l = tid & 63;
    const int w = tid >> 6;
    const int wr = w >> 2;        // 0..1
    const int wc = w & 3;         // 0..3

    const int bid = blockIdx.x;
    const int swz = (bid & 7) * 128 + (bid >> 3);
    const int brow = (swz >> 3) * 256;    // 128 M-tiles
    const int bcol = (swz & 7) * 256;     // 8 N-tiles

    // fragment addressing: row r=(l&15) at addr r*64; chunk (l>>4)^((r>>1)&3)
    const unsigned rA = (unsigned)((wr * 64 + (l & 15)) * 64);
    const unsigned rB = 16384u + (unsigned)((wc * 64 + (l & 15)) * 64);
    const unsigned rowkey = (unsigned)(((l & 15) >> 1) & 3);
    const unsigned pck = (((unsigned)(l >> 4)) ^ rowkey) * 16u;

    // staging: thread ti -> row ti>>2 (0..127), phys chunk ti&3,
    // source logical chunk (ti&3)^((row>>1)&3); LDS linear ti*16
    const unsigned srow = (unsigned)(tid >> 2);
    const unsigned schunk = (unsigned)((tid & 3) ^ ((srow >> 1) & 3));
    const unsigned stlds = (unsigned)(tid * 16);

    f32x4 acc[8][4] = {};

#define STAGE_U(mat, baserow, T, h, matofs) do {                                    \
        int T_ = (T); int Ts_ = T_ > 31 ? 31 : T_;                                  \
        unsigned db_ = (unsigned)((T_ & 1) * 32768) + (matofs) + (h) * 8192u;       \
        const unsigned short* g_ = (mat) + (size_t)((baserow) + (h) * 128 + srow) * 1024 \
                                   + Ts_ * 32 + schunk * 8;                         \
        gload_lds16(g_, lds + db_ + stlds);                                         \
    } while (0)

#define LGKM0_SB() do {                                                             \
        asm volatile("s_waitcnt lgkmcnt(0)" ::: "memory");                          \
        __builtin_amdgcn_sched_barrier(0);                                          \
    } while (0)

#define VMCNT_SB(N) do {                                                            \
        asm volatile("s_waitcnt vmcnt(" #N ")" ::: "memory");                       \
        __builtin_amdgcn_sched_barrier(0);                                          \
    } while (0)

#define RD_A4(dst, bufo, MBASE) do {                                                \
        dst[0] = ldsrd((bufo) + rA + ((MBASE) >> 2) * 8192 + 0 * 1024 + pck);       \
        dst[1] = ldsrd((bufo) + rA + ((MBASE) >> 2) * 8192 + 1 * 1024 + pck);       \
        dst[2] = ldsrd((bufo) + rA + ((MBASE) >> 2) * 8192 + 2 * 1024 + pck);       \
        dst[3] = ldsrd((bufo) + rA + ((MBASE) >> 2) * 8192 + 3 * 1024 + pck);       \
    } while (0)

#define RD_B4(dst, bufo) do {                                                       \
        dst[0] = ldsrd((bufo) + rB + 0 * 1024 + pck);                               \
        dst[1] = ldsrd((bufo) + rB + 1 * 1024 + pck);                               \
        dst[2] = ldsrd((bufo) + rB + 2 * 1024 + pck);                               \
        dst[3] = ldsrd((bufo) + rB + 3 * 1024 + pck);                               \
    } while (0)

#define MFMA16(ABASE, AFR, BFR) do {                                                \
        __builtin_amdgcn_s_setprio(1);                                              \
        _Pragma("unroll")                                                           \
        for (int nf = 0; nf < 4; ++nf) {                                            \
            acc[ABASE + 0][nf] = __builtin_amdgcn_mfma_f32_16x16x32_bf16(AFR[0], BFR[nf], acc[ABASE + 0][nf], 0, 0, 0); \
            acc[ABASE + 1][nf] = __builtin_amdgcn_mfma_f32_16x16x32_bf16(AFR[1], BFR[nf], acc[ABASE + 1][nf], 0, 0, 0); \
            acc[ABASE + 2][nf] = __builtin_amdgcn_mfma_f32_16x16x32_bf16(AFR[2], BFR[nf], acc[ABASE + 2][nf], 0, 0, 0); \
            acc[ABASE + 3][nf] = __builtin_amdgcn_mfma_f32_16x16x32_bf16(AFR[3], BFR[nf], acc[ABASE + 3][nf], 0, 0, 0); \
        }                                                                           \
        __builtin_amdgcn_s_setprio(0);                                              \
    } while (0)

    // ---- prologue: tile0 (4 units) -> buf0 ----
    STAGE_U(xb,   brow, 0, 0, 0u);        // Ah0(0)
    STAGE_U(wcat, bcol, 0, 0, 16384u);    // Bh0(0)
    STAGE_U(wcat, bcol, 0, 1, 16384u);    // Bh1(0)
    STAGE_U(xb,   brow, 0, 1, 0u);        // Ah1(0)
    VMCNT_SB(0);
    __builtin_amdgcn_s_barrier();

    for (int t = 0; t < 32; ++t) {
        const unsigned bufo = (unsigned)((t & 1) * 32768);
        bf16x8 aL[4], aH[4], b[4];

        // ---- P0: mf0-3 x full k ----
        RD_A4(aL, bufo, 0);
        RD_B4(b, bufo);
        STAGE_U(xb,   brow, t + 1, 0, 0u);        // Ah0(t+1) -> nbuf
        STAGE_U(wcat, bcol, t + 1, 0, 16384u);    // Bh0(t+1) -> nbuf
        STAGE_U(wcat, bcol, t + 1, 1, 16384u);    // Bh1(t+1) -> nbuf
        VMCNT_SB(3);                              // drains Ah1(t); 3 new fly
        __builtin_amdgcn_s_barrier();             // publishes Ah1(t)
        LGKM0_SB();
        MFMA16(0, aL, b);

        // ---- P1: mf4-7 x full k (b held) ----
        RD_A4(aH, bufo, 4);                       // reads Ah1(t), published above
        STAGE_U(xb, brow, t + 1, 1, 0u);          // Ah1(t+1) -> nbuf
        VMCNT_SB(1);                              // drains Ah0/Bh0/Bh1(t+1); Ah1(t+1) flies
        __builtin_amdgcn_s_barrier();             // publishes tile t+1 minus Ah1
        LGKM0_SB();
        MFMA16(4, aH, b);
    }

    // drain all LDS-DMA before reusing LDS as the C-transpose buffer
    asm volatile("s_waitcnt vmcnt(0)" ::: "memory");
    __builtin_amdgcn_s_barrier();

    // ---- C-write: two-pass 64KB LDS transpose, then coalesced out ----
    unsigned short* tlds = (unsigned short*)lds;
    unsigned short* og = (unsigned short*)zout;
    const bool is_z = (bcol < 1024);
    #pragma unroll
    for (int half = 0; half < 2; ++half) {
        {
            const int crow = wr * 64 + (l >> 4) * 4;
            const int ccol = wc * 64 + (l & 15);
            #pragma unroll
            for (int nf = 0; nf < 4; ++nf) {
                int col = ccol + nf * 16;
                float bb = is_z ? bias[bcol + col] : 0.f;
                #pragma unroll
                for (int m4 = 0; m4 < 4; ++m4) {
                    int row = crow + m4 * 16;                 // 0..127 local
                    f32x4 v = acc[half * 4 + m4][nf];
                    #pragma unroll
                    for (int j = 0; j < 4; ++j)
                        tlds[(row + j) * 256 + col] = f2bf(v[j] + bb);
                }
            }
        }
        __syncthreads();
        {
            const int rr = tid >> 5;           // 0..15
            const int c16 = (tid & 31) * 8;    // u16 col within 256
            #pragma unroll
            for (int p = 0; p < 8; ++p) {
                int row = p * 16 + rr;          // 0..127 local
                u16x8 v = *(const u16x8*)&tlds[row * 256 + c16];
                *(u16x8*)&og[(size_t)(brow + half * 128 + row) * 2048 + bcol + c16] = v;
            }
        }
        __syncthreads();
    }
#undef STAGE_U
#undef LGKM0_SB
#undef VMCNT_SB
#undef RD_A4
#undef RD_B4
#undef MFMA16
}

// ---------- kernel 5: in-place norm-clamp epilogue ----------
// d_out row r arrives as packed bf16 [1024 z | 1024 m]; leaves as 1024 fp32.
__global__ __launch_bounds__(256) void epilogue_ip(float* out, const int* __restrict__ lidx) {
    int row = blockIdx.x;            // 32768
    int tx = threadIdx.x;            // 256
    const unsigned short* io = (const unsigned short*)out;
    size_t base = (size_t)row * 2048;

    ushort4 zv = *(const ushort4*)&io[base + tx * 4];
    ushort4 mv = *(const ushort4*)&io[base + 1024 + tx * 4];
    float z0 = bf2f(zv.x), z1 = bf2f(zv.y), z2 = bf2f(zv.z), z3 = bf2f(zv.w);
    float m0 = bf2f(mv.x), m1 = bf2f(mv.y), m2 = bf2f(mv.z), m3 = bf2f(mv.w);

    float sz = z0 * z0 + z1 * z1 + z2 * z2 + z3 * z3;
    float sm = m0 * m0 + m1 * m1 + m2 * m2 + m3 * m3;

    #pragma unroll
    for (int off = 32; off > 0; off >>= 1) {
        sz += __shfl_xor(sz, off);
        sm += __shfl_xor(sm, off);
    }
    __shared__ float red[8];
    int wv = tx >> 6;
    if ((tx & 63) == 0) { red[wv * 2] = sz; red[wv * 2 + 1] = sm; }
    __syncthreads();   // also orders: ALL row reads complete before ANY writes
    sz = red[0] + red[2] + red[4] + red[6];
    sm = red[1] + red[3] + red[5] + red[7];

    float gamma = fminf(0.5f * sqrtf(sz) / (sqrtf(sm) + 1e-6f), 1.0f);
    if (lidx[0] < 0) gamma = 0.f;

    float4 o;
    o.x = z0 + gamma * m0; o.y = z1 + gamma * m1;
    o.z = z2 + gamma * m2; o.w = z3 + gamma * m3;
    *(float4*)&out[(size_t)row * 1024 + tx * 4] = o;
}

// ---------- launcher ----------
extern "C" void kernel_launch(void* const* d_in, const int* in_sizes, int n_in,
                              void* d_out, int out_size, void* d_ws, size_t ws_size,
                              hipStream_t stream) {
    const float* x  = (const float*)d_in[0];
    const float* W  = (const float*)d_in[1];
    const float* b  = (const float*)d_in[2];
    const float* A  = (const float*)d_in[3];
    const float* Bm = (const float*)d_in[4];
    const float* sc = (const float*)d_in[5];
    const int* lidx = (const int*)d_in[6];
    float* out = (float*)d_out;

    // ws layout (bytes): xb 64MB | wcat 4MB | acat 512KB | bcatT 512KB
    unsigned short* xb    = (unsigned short*)d_ws;
    unsigned short* wcat  = (unsigned short*)((char*)d_ws + 67108864);
    unsigned short* acat  = (unsigned short*)((char*)d_ws + 71303168);
    unsigned short* bcatT = (unsigned short*)((char*)d_ws + 71827456);

    hipFuncSetAttribute((const void*)gemm_2b,
                        hipFuncAttributeMaxDynamicSharedMemorySize, 65536);

    cast_x<<<16384, 256, 0, stream>>>(x, xb);
    prep_all<<<1152, 256, 0, stream>>>(W, A, Bm, sc, wcat, acat, bcatT);
    mini_gemm<<<64, 256, 32768, stream>>>(bcatT, acat, wcat);
    gemm_2b<<<1024, 512, 65536, stream>>>(xb, wcat, b, out);
    epilogue_ip<<<32768, 256, 0, stream>>>(out, lidx);
}

// Round 16
// 212.864 us; speedup vs baseline: 6.0933x; 6.0933x over previous
//
#include <hip/hip_runtime.h>

// ---------- helpers ----------
typedef __attribute__((ext_vector_type(8))) __bf16 bf16x8;
typedef __attribute__((ext_vector_type(8))) unsigned short u16x8;
typedef __attribute__((ext_vector_type(4))) float f32x4;

__device__ inline unsigned short f2bf(float f) {
    union { float f; unsigned int i; } v; v.f = f;
    unsigned int i = v.i;
    unsigned int r = i + 0x7FFFu + ((i >> 16) & 1u);   // RNE
    return (unsigned short)(r >> 16);
}
__device__ inline float bf2f(unsigned short u) {
    union { unsigned int i; float f; } v; v.i = ((unsigned int)u) << 16; return v.f;
}

__device__ inline void gload_lds16(const void* g, void* l) {
    __builtin_amdgcn_global_load_lds(
        (const __attribute__((address_space(1))) unsigned int*)g,
        (__attribute__((address_space(3))) unsigned int*)l, 16, 0, 0);
}

// inline-asm LDS read (32-bit byte offset, dynamic-LDS base 0); invisible to
// the memory legalizer -> no compiler vmcnt/lgkm drains against our pipeline.
__device__ inline bf16x8 ldsrd(unsigned off) {
    bf16x8 r;
    asm volatile("ds_read_b128 %0, %1" : "=v"(r) : "v"(off));
    return r;
}

// ---------- kernel 1: fused prep — cast x | cast W | acat | bcatT ----------
// blocks 0..16383    : xb = bf16(x), 8 elems/thread (the big 192MB stream)
// blocks 16384..17407: wcat rows 0..1023 = bf16(W)
// blocks 17408..17471: acat[d][e*16+r] = p_e * A[e][d][r]   (bf16 [1024][256])
// blocks 17472..17535: bcatT[D][er] = Bm[er][D]             (bf16 [1024][256])
// Block-uniform branch; small streams overlap the big one instead of serializing.
__global__ __launch_bounds__(256) void prep_all(const float* __restrict__ x,
                                                const float* __restrict__ W,
                                                const float* __restrict__ A,
                                                const float* __restrict__ Bm,
                                                const float* __restrict__ scores,
                                                unsigned short* __restrict__ xb,
                                                unsigned short* __restrict__ wcat,
                                                unsigned short* __restrict__ acat,
                                                unsigned short* __restrict__ bcatT) {
    const int blk = blockIdx.x;
    const int tx = threadIdx.x;
    if (blk < 16384) {
        size_t i = ((size_t)blk * 256 + tx) * 8;
        float4 v0 = *(const float4*)&x[i];
        float4 v1 = *(const float4*)&x[i + 4];
        ushort4 o0, o1;
        o0.x = f2bf(v0.x); o0.y = f2bf(v0.y); o0.z = f2bf(v0.z); o0.w = f2bf(v0.w);
        o1.x = f2bf(v1.x); o1.y = f2bf(v1.y); o1.z = f2bf(v1.z); o1.w = f2bf(v1.w);
        *(ushort4*)&xb[i] = o0;
        *(ushort4*)&xb[i + 4] = o1;
    } else if (blk < 17408) {
        int i = (blk - 16384) * 256 + tx;
        float4 v = ((const float4*)W)[i];
        ushort4 o;
        o.x = f2bf(v.x); o.y = f2bf(v.y); o.z = f2bf(v.z); o.w = f2bf(v.w);
        ((ushort4*)wcat)[i] = o;
    } else if (blk < 17472) {
        int tid = (blk - 17408) * 256 + tx;     // 16384
        int e = tid >> 10;
        int d = tid & 1023;
        float pe = scores[e];
        const float4* src = (const float4*)(A + (size_t)e * 16384 + (size_t)d * 16);
        unsigned short* dst = acat + (size_t)d * 256 + e * 16;
        #pragma unroll
        for (int q = 0; q < 4; ++q) {
            float4 v = src[q];
            ushort4 o;
            o.x = f2bf(pe * v.x); o.y = f2bf(pe * v.y);
            o.z = f2bf(pe * v.z); o.w = f2bf(pe * v.w);
            *(ushort4*)(dst + q * 4) = o;
        }
    } else {
        __shared__ float t[64][65];
        const int bb = blk - 17472;             // 0..63
        const int Dt = (bb & 15) * 64;          // D tile
        const int et = (bb >> 4) * 64;          // er tile
        {
            const int i = tx >> 2;              // er row 0..63
            const int c4 = (tx & 3) * 16;       // D col base
            const float* src = Bm + (size_t)(et + i) * 1024 + Dt + c4;
            #pragma unroll
            for (int q = 0; q < 4; ++q) {
                float4 v = *(const float4*)(src + q * 4);
                t[i][c4 + q * 4 + 0] = v.x; t[i][c4 + q * 4 + 1] = v.y;
                t[i][c4 + q * 4 + 2] = v.z; t[i][c4 + q * 4 + 3] = v.w;
            }
        }
        __syncthreads();
        {
            const int j = tx >> 2;              // D row 0..63
            const int seg = (tx & 3) * 16;      // er col base
            unsigned short* dst = bcatT + (size_t)(Dt + j) * 256 + et + seg;
            #pragma unroll
            for (int q = 0; q < 16; ++q)
                dst[q] = f2bf(t[seg + q][j]);
        }
    }
}

// ---------- kernel 2: mini GEMM  wcat[1024+D][d] = sum_k bcatT[D][k]*acat[d][k] ----------
__global__ __launch_bounds__(256) void mini_gemm(const unsigned short* __restrict__ bcatT,
                                                 const unsigned short* __restrict__ acat,
                                                 unsigned short* __restrict__ wcat) {
    extern __shared__ char lds[];
    const int tid = threadIdx.x;
    const int l = tid & 63;
    const int w = tid >> 6;
    const int wr = w >> 1;        // 0..1 (D half)
    const int wc = w & 1;         // 0..1 (d half)

    const int trow = (blockIdx.x >> 3) * 128;   // D tile
    const int tcol = (blockIdx.x & 7) * 128;    // d tile

    const unsigned rA128 = (unsigned)((wr * 64 + (l & 15)) * 128);
    const unsigned rB128 = 16384u + (unsigned)((wc * 64 + (l & 15)) * 128);
    const unsigned pck0 = (((l >> 4)) ^ (l & 7)) * 16u;
    const unsigned pck1 = ((4 + (l >> 4)) ^ (l & 7)) * 16u;

    const unsigned strow = (unsigned)(tid >> 3);               // 0..31
    const unsigned stchunk = (unsigned)((tid & 7) ^ (strow & 7));
    const unsigned stlds = (unsigned)(tid * 16);

    f32x4 acc[4][4] = {};

    for (int t = 0; t < 4; ++t) {
        #pragma unroll
        for (int h = 0; h < 4; ++h) {
            const unsigned short* ga = bcatT + (size_t)(trow + h * 32 + strow) * 256 + t * 64 + stchunk * 8;
            const unsigned short* gb = acat  + (size_t)(tcol + h * 32 + strow) * 256 + t * 64 + stchunk * 8;
            gload_lds16(ga, lds + h * 4096 + stlds);
            gload_lds16(gb, lds + 16384 + h * 4096 + stlds);
        }
        asm volatile("s_waitcnt vmcnt(0)" ::: "memory");
        __builtin_amdgcn_s_barrier();

        bf16x8 a[4], b[4];
        #pragma unroll
        for (int ks = 0; ks < 2; ++ks) {
            const unsigned pck = ks ? pck1 : pck0;
            #pragma unroll
            for (int mf = 0; mf < 4; ++mf) a[mf] = ldsrd(rA128 + mf * 2048 + pck);
            #pragma unroll
            for (int nf = 0; nf < 4; ++nf) b[nf] = ldsrd(rB128 + nf * 2048 + pck);
            asm volatile("s_waitcnt lgkmcnt(0)" ::: "memory");
            __builtin_amdgcn_sched_barrier(0);
            #pragma unroll
            for (int mf = 0; mf < 4; ++mf)
                #pragma unroll
                for (int nf = 0; nf < 4; ++nf)
                    acc[mf][nf] = __builtin_amdgcn_mfma_f32_16x16x32_bf16(a[mf], b[nf], acc[mf][nf], 0, 0, 0);
        }
        __builtin_amdgcn_s_barrier();
    }

    const int crow0 = trow + wr * 64 + (l >> 4) * 4;   // D
    const int ccol0 = tcol + wc * 64 + (l & 15);       // d
    #pragma unroll
    for (int mf = 0; mf < 4; ++mf) {
        int D = crow0 + mf * 16;
        #pragma unroll
        for (int nf = 0; nf < 4; ++nf) {
            int d = ccol0 + nf * 16;
            f32x4 v = acc[mf][nf];
            #pragma unroll
            for (int j = 0; j < 4; ++j)
                wcat[(size_t)(1024 + D + j) * 1024 + d] = f2bf(v[j]);
        }
    }
}

// ---------- kernel 3: 256x256-tile GEMM, 4-phase + counted cross-tile vmcnt (R12/R14) ----------
__global__ __launch_bounds__(512, 2) void gemm_zm4(const unsigned short* __restrict__ xb,
                                                   const unsigned short* __restrict__ wcat,
                                                   const float* __restrict__ bias,
                                                   float* __restrict__ zout) {
    extern __shared__ char lds[];
    const int tid = threadIdx.x;
    const int l = tid & 63;
    const int w = tid >> 6;
    const int wr = w >> 2;        // 0..1
    const int wc = w & 3;         // 0..3

    const int bid = blockIdx.x;
    const int swz = (bid & 7) * 128 + (bid >> 3);
    const int brow = (swz >> 3) * 256;    // 128 M-tiles
    const int bcol = (swz & 7) * 256;     // 8 N-tiles

    const unsigned rA128 = (unsigned)((wr * 64 + (l & 15)) * 128);
    const unsigned rB128 = 32768u + (unsigned)((wc * 64 + (l & 15)) * 128);
    const unsigned pck0 = (((l >> 4)) ^ (l & 7)) * 16u;
    const unsigned pck1 = ((4 + (l >> 4)) ^ (l & 7)) * 16u;

    const unsigned strow = (unsigned)(tid >> 3);
    const unsigned stchunk = (unsigned)((tid & 7) ^ (strow & 7));
    const unsigned stlds = (unsigned)(tid * 16);

    f32x4 acc[8][4] = {};

#define STAGE(mat, baserow, T, h, bofs) do {                                        \
        int T_ = (T); int Ts_ = T_ > 15 ? 15 : T_;                                  \
        unsigned db_ = (unsigned)((T_ & 1) * 65536) + (bofs) + (h) * 16384u;        \
        const unsigned short* g_ = (mat) + (size_t)((baserow) + (h) * 128 + strow) * 1024 \
                                   + Ts_ * 64 + stchunk * 8;                        \
        gload_lds16(g_,           lds + db_ + stlds);                               \
        gload_lds16(g_ + 64*1024, lds + db_ + 8192 + stlds);                        \
    } while (0)

#define LGKM0_SB() do {                                                             \
        asm volatile("s_waitcnt lgkmcnt(0)" ::: "memory");                          \
        __builtin_amdgcn_sched_barrier(0);                                          \
    } while (0)

#define VMCNT_SB(N) do {                                                            \
        asm volatile("s_waitcnt vmcnt(" #N ")" ::: "memory");                       \
        __builtin_amdgcn_sched_barrier(0);                                          \
    } while (0)

#define RD_A4(dst, bufo, MBASE, PCK) do {                                           \
        dst[0] = ldsrd((bufo) + rA128 + ((MBASE + 0) & 3) * 2048 + ((MBASE + 0) >> 2) * 16384 + (PCK)); \
        dst[1] = ldsrd((bufo) + rA128 + ((MBASE + 1) & 3) * 2048 + ((MBASE + 1) >> 2) * 16384 + (PCK)); \
        dst[2] = ldsrd((bufo) + rA128 + ((MBASE + 2) & 3) * 2048 + ((MBASE + 2) >> 2) * 16384 + (PCK)); \
        dst[3] = ldsrd((bufo) + rA128 + ((MBASE + 3) & 3) * 2048 + ((MBASE + 3) >> 2) * 16384 + (PCK)); \
    } while (0)

#define RD_B4(dst, bufo, PCK) do {                                                  \
        dst[0] = ldsrd((bufo) + rB128 + 0 * 2048 + (PCK));                          \
        dst[1] = ldsrd((bufo) + rB128 + 1 * 2048 + (PCK));                          \
        dst[2] = ldsrd((bufo) + rB128 + 2 * 2048 + (PCK));                          \
        dst[3] = ldsrd((bufo) + rB128 + 3 * 2048 + (PCK));                          \
    } while (0)

#define MFMA16(ABASE, AFR, BFR) do {                                                \
        __builtin_amdgcn_s_setprio(1);                                              \
        _Pragma("unroll")                                                           \
        for (int nf = 0; nf < 4; ++nf) {                                            \
            acc[ABASE + 0][nf] = __builtin_amdgcn_mfma_f32_16x16x32_bf16(AFR[0], BFR[nf], acc[ABASE + 0][nf], 0, 0, 0); \
            acc[ABASE + 1][nf] = __builtin_amdgcn_mfma_f32_16x16x32_bf16(AFR[1], BFR[nf], acc[ABASE + 1][nf], 0, 0, 0); \
            acc[ABASE + 2][nf] = __builtin_amdgcn_mfma_f32_16x16x32_bf16(AFR[2], BFR[nf], acc[ABASE + 2][nf], 0, 0, 0); \
            acc[ABASE + 3][nf] = __builtin_amdgcn_mfma_f32_16x16x32_bf16(AFR[3], BFR[nf], acc[ABASE + 3][nf], 0, 0, 0); \
        }                                                                           \
        __builtin_amdgcn_s_setprio(0);                                              \
    } while (0)

    // ---- prologue: tile0 staged [Ah0,Bh0,Bh1,Ah1]; vmcnt(2) leaves Ah1 flying ----
    STAGE(xb,   brow, 0, 0, 0u);        // Ah0(0)
    STAGE(wcat, bcol, 0, 0, 32768u);    // Bh0(0)
    STAGE(wcat, bcol, 0, 1, 32768u);    // Bh1(0)
    STAGE(xb,   brow, 0, 1, 0u);        // Ah1(0)
    VMCNT_SB(2);
    __builtin_amdgcn_s_barrier();

    for (int t = 0; t < 16; ++t) {
        const unsigned bufo = (unsigned)((t & 1) * 65536);
        bf16x8 aL[4], aL2[4], aH[4], aH2[4], b0[4], b1[4];

        // ---- P0: k0 x Ah0 ----
        RD_A4(aL, bufo, 0, pck0);
        RD_B4(b0, bufo, pck0);
        STAGE(xb, brow, t + 1, 0, 0u);          // Ah0(t+1)
        __builtin_amdgcn_s_barrier();
        LGKM0_SB();
        MFMA16(0, aL, b0);

        // ---- P1: k1 x Ah0 ----
        RD_A4(aL2, bufo, 0, pck1);
        RD_B4(b1, bufo, pck1);
        STAGE(wcat, bcol, t + 1, 0, 32768u);    // Bh0(t+1)
        VMCNT_SB(4);                            // own Ah1(t) landed; 4 newer fly
        __builtin_amdgcn_s_barrier();           // publishes Ah1(t)
        LGKM0_SB();
        MFMA16(0, aL2, b1);

        // ---- P2: k0 x Ah1 (b0 held) ----
        RD_A4(aH, bufo, 4, pck0);
        STAGE(wcat, bcol, t + 1, 1, 32768u);    // Bh1(t+1)
        __builtin_amdgcn_s_barrier();
        LGKM0_SB();
        MFMA16(4, aH, b0);

        // ---- P3: k1 x Ah1 (b1 held) ----
        RD_A4(aH2, bufo, 4, pck1);
        STAGE(xb, brow, t + 1, 1, 0u);          // Ah1(t+1)
        VMCNT_SB(2);                            // Ah0,Bh0,Bh1(t+1) landed; Ah1(t+1) flies
        __builtin_amdgcn_s_barrier();           // publishes tile t+1 minus Ah1
        LGKM0_SB();
        MFMA16(4, aH2, b1);
    }

    // drain all LDS-DMA before reusing LDS as the C-transpose buffer
    asm volatile("s_waitcnt vmcnt(0)" ::: "memory");
    __builtin_amdgcn_s_barrier();

    // ---- C-write: scatter acc -> LDS [256][256] bf16, then coalesced out ----
    unsigned short* tlds = (unsigned short*)lds;
    const bool is_z = (bcol < 1024);
    {
        const int crow = wr * 64 + (l >> 4) * 4;
        const int ccol = wc * 64 + (l & 15);
        #pragma unroll
        for (int nf = 0; nf < 4; ++nf) {
            int col = ccol + nf * 16;
            float bb = is_z ? bias[bcol + col] : 0.f;
            #pragma unroll
            for (int mf = 0; mf < 8; ++mf) {
                int row = crow + (mf & 3) * 16 + (mf >> 2) * 128;
                f32x4 v = acc[mf][nf];
                #pragma unroll
                for (int j = 0; j < 4; ++j)
                    tlds[(row + j) * 256 + col] = f2bf(v[j] + bb);
            }
        }
    }
    __syncthreads();
    {
        // d_out as packed bf16: row r = [1024 z | 1024 m] (u16 units, 2048/row)
        unsigned short* og = (unsigned short*)zout;
        const int rr = tid >> 5;           // 0..15
        const int c16 = (tid & 31) * 8;    // u16 col within 256
        #pragma unroll
        for (int p = 0; p < 16; ++p) {
            int row = p * 16 + rr;
            u16x8 v = *(const u16x8*)&tlds[row * 256 + c16];
            *(u16x8*)&og[(size_t)(brow + row) * 2048 + bcol + c16] = v;
        }
    }
#undef STAGE
#undef LGKM0_SB
#undef VMCNT_SB
#undef RD_A4
#undef RD_B4
#undef MFMA16
}

// ---------- kernel 4: in-place norm-clamp epilogue ----------
// d_out row r arrives as packed bf16 [1024 z | 1024 m]; leaves as 1024 fp32.
__global__ __launch_bounds__(256) void epilogue_ip(float* out, const int* __restrict__ lidx) {
    int row = blockIdx.x;            // 32768
    int tx = threadIdx.x;            // 256
    const unsigned short* io = (const unsigned short*)out;
    size_t base = (size_t)row * 2048;

    ushort4 zv = *(const ushort4*)&io[base + tx * 4];
    ushort4 mv = *(const ushort4*)&io[base + 1024 + tx * 4];
    float z0 = bf2f(zv.x), z1 = bf2f(zv.y), z2 = bf2f(zv.z), z3 = bf2f(zv.w);
    float m0 = bf2f(mv.x), m1 = bf2f(mv.y), m2 = bf2f(mv.z), m3 = bf2f(mv.w);

    float sz = z0 * z0 + z1 * z1 + z2 * z2 + z3 * z3;
    float sm = m0 * m0 + m1 * m1 + m2 * m2 + m3 * m3;

    #pragma unroll
    for (int off = 32; off > 0; off >>= 1) {
        sz += __shfl_xor(sz, off);
        sm += __shfl_xor(sm, off);
    }
    __shared__ float red[8];
    int wv = tx >> 6;
    if ((tx & 63) == 0) { red[wv * 2] = sz; red[wv * 2 + 1] = sm; }
    __syncthreads();   // also orders: ALL row reads complete before ANY writes
    sz = red[0] + red[2] + red[4] + red[6];
    sm = red[1] + red[3] + red[5] + red[7];

    float gamma = fminf(0.5f * sqrtf(sz) / (sqrtf(sm) + 1e-6f), 1.0f);
    if (lidx[0] < 0) gamma = 0.f;

    float4 o;
    o.x = z0 + gamma * m0; o.y = z1 + gamma * m1;
    o.z = z2 + gamma * m2; o.w = z3 + gamma * m3;
    *(float4*)&out[(size_t)row * 1024 + tx * 4] = o;
}

// ---------- launcher ----------
extern "C" void kernel_launch(void* const* d_in, const int* in_sizes, int n_in,
                              void* d_out, int out_size, void* d_ws, size_t ws_size,
                              hipStream_t stream) {
    const float* x  = (const float*)d_in[0];
    const float* W  = (const float*)d_in[1];
    const float* b  = (const float*)d_in[2];
    const float* A  = (const float*)d_in[3];
    const float* Bm = (const float*)d_in[4];
    const float* sc = (const float*)d_in[5];
    const int* lidx = (const int*)d_in[6];
    float* out = (float*)d_out;

    // ws layout (bytes): xb 64MB | wcat 4MB | acat 512KB | bcatT 512KB
    unsigned short* xb    = (unsigned short*)d_ws;
    unsigned short* wcat  = (unsigned short*)((char*)d_ws + 67108864);
    unsigned short* acat  = (unsigned short*)((char*)d_ws + 71303168);
    unsigned short* bcatT = (unsigned short*)((char*)d_ws + 71827456);

    hipFuncSetAttribute((const void*)gemm_zm4,
                        hipFuncAttributeMaxDynamicSharedMemorySize, 131072);

    prep_all<<<17536, 256, 0, stream>>>(x, W, A, Bm, sc, xb, wcat, acat, bcatT);
    mini_gemm<<<64, 256, 32768, stream>>>(bcatT, acat, wcat);
    gemm_zm4<<<1024, 512, 131072, stream>>>(xb, wcat, b, out);
    epilogue_ip<<<32768, 256, 0, stream>>>(out, lidx);
}